// Round 8
// baseline (579.431 us; speedup 1.0000x reference)
//
#include <hip/hip_runtime.h>
#include <stdint.h>

// ---------------- common helpers ----------------

using f32x4 = __attribute__((ext_vector_type(4))) float;
using f32x16 = __attribute__((ext_vector_type(16))) float;
using s16x8 = __attribute__((ext_vector_type(8))) short;

__device__ __forceinline__ ushort f2b(float f) {
    union { float f; uint32_t u; } v; v.f = f;
    uint32_t u = v.u;
    return (ushort)((u + 0x7fffu + ((u >> 16) & 1u)) >> 16);
}
__device__ __forceinline__ float b2f(ushort b) {
    union { uint32_t u; float f; } v; v.u = ((uint32_t)b) << 16;
    return v.f;
}
__device__ __forceinline__ float to_f(float f) { return f; }
__device__ __forceinline__ float to_f(ushort b) { return b2f(b); }

// async global->LDS, 16B per lane; LDS dest = wave-uniform base + lane*16
__device__ __forceinline__ void async_ld16(const ushort* g, ushort* l) {
    __builtin_amdgcn_global_load_lds(
        (const __attribute__((address_space(1))) void*)g,
        (__attribute__((address_space(3))) void*)l,
        16, 0, 0);
}

// s_waitcnt immediates (gfx9): vmcnt[3:0]|[15:14], expcnt[6:4], lgkmcnt[11:8]
#define WAITCNT_VM4    0x0F74  // vmcnt=4, lgkm/exp no-wait
#define WAITCNT_VM0    0x0F70  // vmcnt=0
#define WAITCNT_LGKM0  0xC07F  // lgkmcnt=0, vmcnt/exp no-wait

// ---------------- cast fp32 -> bf16 (vectorized x4) ----------------

__global__ __launch_bounds__(256) void cast_f2b4(const float* __restrict__ src,
                                                 ushort* __restrict__ dst,
                                                 long long n4) {
    long long i = (long long)blockIdx.x * 256 + threadIdx.x;
    if (i >= n4) return;
    float4 f = ((const float4*)src)[i];
    ushort4 o;
    o.x = f2b(f.x); o.y = f2b(f.y); o.z = f2b(f.z); o.w = f2b(f.w);
    ((ushort4*)dst)[i] = o;
}

// ---------------- bias concat: [bq|bk|bv] -> dst (3*1024 floats) ----------------

__global__ __launch_bounds__(256) void concat3(const float* __restrict__ a,
                                               const float* __restrict__ b,
                                               const float* __restrict__ c,
                                               float* __restrict__ dst) {
    int i = blockIdx.x * 256 + threadIdx.x;  // grid 12 blocks = 3072
    const float* s = (i < 1024) ? a : (i < 2048) ? b : c;
    dst[i] = s[i & 1023];
}

// ---------------- split-K partial reduce + cast to bf16 --------------------------

__global__ __launch_bounds__(256) void add2_cast(const float* __restrict__ a,
                                                 const float* __restrict__ b,
                                                 ushort* __restrict__ o,
                                                 long long n4) {
    long long i = (long long)blockIdx.x * 256 + threadIdx.x;
    if (i >= n4) return;
    float4 x = ((const float4*)a)[i];
    float4 y = ((const float4*)b)[i];
    ushort4 u;
    u.x = f2b(x.x + y.x); u.y = f2b(x.y + y.y);
    u.z = f2b(x.z + y.z); u.w = f2b(x.w + y.w);
    ((ushort4*)o)[i] = u;
}

// ---------------- transpose (fp32 or bf16 in) -> bf16 out ----------------
// src: [R][C] with row stride srcLd, dst: [C][R] row-major.
// Grid: (C/32, R/32, batch), block (32,8).

template <typename T>
__global__ __launch_bounds__(256) void transpose_to_bf16(const T* __restrict__ src,
                                                         ushort* __restrict__ dst,
                                                         int R, int C, int srcLd,
                                                         long long ss, long long ds) {
    __shared__ float tile[32][33];
    src += (long long)blockIdx.z * ss;
    dst += (long long)blockIdx.z * ds;
    const int c0 = blockIdx.x * 32;
    const int r0 = blockIdx.y * 32;
    const int tx = threadIdx.x, ty = threadIdx.y;
#pragma unroll
    for (int i = 0; i < 4; i++) {
        int r = r0 + ty + i * 8;
        tile[ty + i * 8][tx] = to_f(src[(long long)r * srcLd + c0 + tx]);
    }
    __syncthreads();
#pragma unroll
    for (int i = 0; i < 4; i++) {
        int r = c0 + ty + i * 8;  // row of dst, in [0, C)
        dst[(long long)r * R + r0 + tx] = f2b(tile[tx][ty + i * 8]);
    }
}

// ---- fused 4x (1024x1024) transpose-cast: z selects {wq,wk,wv,wo}, dst contiguous ----

__global__ __launch_bounds__(256) void transpose4_to_bf16(const float* __restrict__ s0,
                                                          const float* __restrict__ s1,
                                                          const float* __restrict__ s2,
                                                          const float* __restrict__ s3,
                                                          ushort* __restrict__ dst) {
    __shared__ float tile[32][33];
    const int D = 1024;
    const int z = blockIdx.z;
    const float* src = (z == 0) ? s0 : (z == 1) ? s1 : (z == 2) ? s2 : s3;
    dst += (long long)z * D * D;
    const int c0 = blockIdx.x * 32;
    const int r0 = blockIdx.y * 32;
    const int tx = threadIdx.x, ty = threadIdx.y;
#pragma unroll
    for (int i = 0; i < 4; i++) {
        int r = r0 + ty + i * 8;
        tile[ty + i * 8][tx] = src[(long long)r * D + c0 + tx];
    }
    __syncthreads();
#pragma unroll
    for (int i = 0; i < 4; i++) {
        int r = c0 + ty + i * 8;
        dst[(long long)r * D + r0 + tx] = f2b(tile[tx][ty + i * 8]);
    }
}

// ---------------- bf16 MFMA GEMM, 256x256 tile, 8-phase, 32x32x16 MFMA -----------
// C[M,N] = A[M,K] * BT[N,K]^T (+bias, relu, scale). 512 threads = 8 waves (2M x 4N),
// per-wave 128x64 output. LDS: 4 x 32KB BK=32 bufs; a PAIR = one BK=64 tile.
// Bank swizzle phys_slot = log_slot ^ ((row>>1)&3) both sides (R4: conflicts = 0).
// Phase/sync/staging discipline = R6 (race-screened): 4 phases/pair, each
// {ds_reads; stage 1 unit; barrier; lgkm0; setprio1; MFMA; setprio0; barrier};
// counted vm4 only at ph2/ph4; last pair vm0@ph2, no stages.
//
// R8 change (R7 post-mortem: WAR-split regressed -> reverted; LDS-BW+MFMA-floor
// re-budget): switch to v_mfma_f32_32x32x16_bf16 -- measured ceiling 2495 TF vs
// 2075 for 16x16x32 (m119/m06, ~17% cheaper/FLOP) and HALF the MFMA instruction
// count (8/phase vs 16). acc = f32x16[4][2] (tile_m x tile_n of 32x32), reads
// balanced 6 b128/phase (4 A + 2 B per K16-half). Same LDS traffic; same swizzle
// (re-derived: 8-lane pass covers all 8 bank quartets once).
// A/B frag: lane -> row lane&31, k-octet lane>>5 (family-consistent with the
// verified 16x16 mapping). C/D: col=lane&31, row=(reg&3)+8*(reg>>2)+4*(lane>>5)
// [HW-verified m74/m101]. Epilogue stagings remapped; readout passes unchanged.
// Split-K (kChunks>1): chunk kIdx writes partials at C + kIdx*sK; bias chunk 0 only.

template <int OUT_BF16, int RELU, int HAS_BIAS>
__global__ __launch_bounds__(512, 2) void gemm256(const ushort* __restrict__ A,
                                                  const ushort* __restrict__ BT,
                                                  void* __restrict__ Cp,
                                                  const float* __restrict__ bias,
                                                  int K, int kChunks, float scale,
                                                  int lda, int ldb, int ldc,
                                                  long long sA, long long sB,
                                                  long long sC, long long sK) {
    __shared__ ushort SH[65536];   // 128 KB: A bufs [4][256][32] @0, B bufs @+32768 elems
    ushort* Asl = SH;
    ushort* Bsl = SH + 32768;

    const int tid = threadIdx.x;
    const int kIdx = blockIdx.z % kChunks;
    const int bz = blockIdx.z / kChunks;
    const int kLen = K / kChunks;
    const int kOff = kIdx * kLen;
    const int kTiles = kLen >> 5;   // BK=32; call sites give kTiles in {16,32,64}
    const ushort* Ab = A + (long long)bz * sA;
    const ushort* Bb = BT + (long long)bz * sB;

    // XCD-panel swizzle (T1; bijective since gridDim.y % 8 == 0 for all our grids)
    const int W = gridDim.x, H = gridDim.y;
    const int bidx = blockIdx.y * W + blockIdx.x;
    const int Hp = H >> 3;
    const int xcd = bidx & 7;
    const int sb = bidx >> 3;
    const int tn = sb / Hp;
    const int tm = xcd * Hp + sb % Hp;

    const int lane = tid & 63;
    const int w = tid >> 6;    // wave 0..7
    const int wm = w >> 2;     // M half 0..1
    const int wn = w & 3;      // N quarter 0..3
    const int lcol = lane & 31;
    const int lhi = lane >> 5;  // 0..1

    // ---- staging: one K32-tile unit = A 16KB (2 gloads/wave) or B 16KB.
    // instr covers 16 rows x 32 cols; lane l -> LDS row (l>>2), phys slot (l&3).
    // Source fetches logical slot (l&3) ^ ((lr>>1)&3)  [bank swizzle, R4-verified].
    const int lr = lane >> 2;                                // 0..15
    const int lc = ((lane & 3) ^ ((lane >> 3) & 3)) * 8;     // swizzled source chunk
    const ushort* AgS = Ab + (long long)(tm * 256 + w * 32 + lr) * lda + kOff + lc;
    const ushort* BgS = Bb + (long long)(tn * 256 + w * 32 + lr) * ldb + kOff + lc;
    ushort* AsW = Asl + w * 1024;    // wave's 32 rows within a buf
    ushort* BsW = Bsl + w * 1024;
    const long long rstepA = (long long)16 * lda;
    const long long rstepB = (long long)16 * ldb;

#define STG_AU(tt, boff) { const ushort* ga_ = AgS + (tt) * 32;                   \
        async_ld16(ga_, AsW + (boff));                                            \
        async_ld16(ga_ + rstepA, AsW + (boff) + 512); }
#define STG_BU(tt, boff) { const ushort* gb_ = BgS + (tt) * 32;                   \
        async_ld16(gb_, BsW + (boff));                                            \
        async_ld16(gb_ + rstepB, BsW + (boff) + 512); }

    // ---- fragment read bases: A row = wm*128 + tm_*32 + lcol; B row = wn*64 +
    // tn_*32 + lcol. logical slot = kh*2 + lhi; phys = logical ^ ((lcol>>1)&3).
    // kh=1 flips slot bit 1 -> element offset XOR 16.
    const int fsl0 = ((lhi) ^ ((lcol >> 1) & 3)) * 8;   // kh=0 slot*8
    const ushort* ArdB0 = Asl + (wm * 128 + lcol) * 32 + fsl0;
    const ushort* ArdB1 = Asl + (wm * 128 + lcol) * 32 + (fsl0 ^ 16);
    const ushort* BrdB0 = Bsl + (wn * 64 + lcol) * 32 + fsl0;
    const ushort* BrdB1 = Bsl + (wn * 64 + lcol) * 32 + (fsl0 ^ 16);

#define LDA4(base, boff) {                                                        \
    _Pragma("unroll") for (int i_ = 0; i_ < 4; i_++)                              \
        fa[i_] = *(const s16x8*)(base + (boff) + i_ * 1024); }
#define LDB2(base, boff) {                                                        \
    _Pragma("unroll") for (int j_ = 0; j_ < 2; j_++)                              \
        fb[j_] = *(const s16x8*)(base + (boff) + j_ * 1024); }
#define MM8() {                                                                   \
    _Pragma("unroll") for (int tm_ = 0; tm_ < 4; tm_++)                           \
    _Pragma("unroll") for (int tn_ = 0; tn_ < 2; tn_++)                           \
        acc[tm_][tn_] = __builtin_amdgcn_mfma_f32_32x32x16_bf16(                  \
            fa[tm_], fb[tn_], acc[tm_][tn_], 0, 0, 0); }

#define BAR   __builtin_amdgcn_s_barrier()
#define PRIO1 __builtin_amdgcn_s_setprio(1)
#define PRIO0 __builtin_amdgcn_s_setprio(0)
#define WVM4  __builtin_amdgcn_s_waitcnt(WAITCNT_VM4)
#define WVM0  __builtin_amdgcn_s_waitcnt(WAITCNT_VM0)
#define WLG0  __builtin_amdgcn_s_waitcnt(WAITCNT_LGKM0)

// One pair = tiles (sub0 in buf c0, sub1 in buf c1); stages next pair's units
// into bufs d0,d1 (tiles t2, t3). LAST pair: no stages, vm0 at ph2.
#define PAIR(c0, c1, d0, d1, t2, t3, LAST) {                                      \
    /* ph1: sub0 kh0 ; stage A-sub0(next) */                                      \
    LDA4(ArdB0, c0); LDB2(BrdB0, c0);                                             \
    if (!(LAST)) STG_AU(t2, d0);                                                  \
    BAR; WLG0; PRIO1; MM8(); PRIO0; BAR;                                          \
    /* ph2: sub0 kh1 ; stage B-sub0(next) ; vm4 drains THIS pair's sub1 */        \
    LDA4(ArdB1, c0); LDB2(BrdB1, c0);                                             \
    if (!(LAST)) STG_BU(t2, d0);                                                  \
    BAR; WLG0; PRIO1; MM8(); PRIO0;                                               \
    if (LAST) { WVM0; } else { WVM4; }                                            \
    BAR;                                                                          \
    /* ph3: sub1 kh0 ; stage A-sub1(next) */                                      \
    LDA4(ArdB0, c1); LDB2(BrdB0, c1);                                             \
    if (!(LAST)) STG_AU(t3, d1);                                                  \
    BAR; WLG0; PRIO1; MM8(); PRIO0; BAR;                                          \
    /* ph4: sub1 kh1 ; stage B-sub1(next) ; vm4 drains NEXT pair's sub0 */        \
    LDA4(ArdB1, c1); LDB2(BrdB1, c1);                                             \
    if (!(LAST)) STG_BU(t3, d1);                                                  \
    BAR; WLG0; PRIO1; MM8(); PRIO0;                                               \
    if (!(LAST)) { WVM4; }                                                        \
    BAR; }

    f32x16 acc[4][2];
#pragma unroll
    for (int i = 0; i < 4; i++)
#pragma unroll
        for (int j = 0; j < 2; j++) acc[i][j] = (f32x16){0.f};

    s16x8 fa[4], fb[2];

    // ---- prologue: stage pair0 (4 units, 8 loads); vm4 lands sub0, sub1 in flight.
    STG_AU(0, 0); STG_BU(0, 0); STG_AU(1, 8192); STG_BU(1, 8192);
    WVM4;
    BAR;

    // ---- pairs: even pair -> bufs (0,1), odd -> (2,3); nP is even, >= 8.
    const int nP = kTiles >> 1;
    int pr = 0;
    for (; pr + 3 <= nP; pr += 2) {
        PAIR(0, 8192, 16384, 24576, 2 * pr + 2, 2 * pr + 3, 0);
        PAIR(16384, 24576, 0, 8192, 2 * pr + 4, 2 * pr + 5, 0);
    }
    // tail: pair nP-2 (stages the last pair), then last pair (no stages)
    PAIR(0, 8192, 16384, 24576, 2 * pr + 2, 2 * pr + 3, 0);
    PAIR(16384, 24576, 0, 8192, 0, 0, 1);

#undef STG_AU
#undef STG_BU
#undef LDA4
#undef LDB2
#undef MM8
#undef PAIR

    BAR;  // all waves' frag reads retired before C-staging reuses SH

    // ---- epilogue: C/D layout col = lane&31, row = (reg&3)+8*(reg>>2)+4*(lane>>5)
    // [m74/m101]. Stage into LDS (group-XOR swizzle -> low-conflict writes,
    // full-row reads), then fully-coalesced global stores (R2-verified).
    const long long cb = (long long)bz * sC + (long long)kIdx * sK;
    if (OUT_BF16) {
        ushort* Cb = (ushort*)Cp;
        // stage: SH as [256 rows][16 groups of 16 ushorts], group ^= (row>>2)&3
#pragma unroll
        for (int tn_ = 0; tn_ < 2; tn_++) {
            const int col = wn * 64 + tn_ * 32 + lcol;  // 0..255
            const float bv = HAS_BIAS ? bias[tn * 256 + col] : 0.0f;
            const int cg = col >> 4, cl16 = col & 15;
#pragma unroll
            for (int tm_ = 0; tm_ < 4; tm_++) {
                const int rbase = wm * 128 + tm_ * 32 + 4 * lhi;
#pragma unroll
                for (int r = 0; r < 16; r++) {
                    const int row = rbase + (r & 3) + 8 * (r >> 2);
                    float v = acc[tm_][tn_][r] * scale + bv;
                    if (RELU) v = v > 0.f ? v : 0.f;
                    SH[row * 256 + ((cg ^ ((row >> 2) & 3)) << 4) + cl16] = f2b(v);
                }
            }
        }
        BAR;
        // readout: 16 passes x (16 rows x 32 chunks of 16B); 512B contiguous/row
        const int crow = tid >> 5;  // 0..15
        const int cch = tid & 31;   // 0..31
        const int g = cch >> 1, hh = cch & 1;
#pragma unroll
        for (int pass = 0; pass < 16; pass++) {
            const int row = pass * 16 + crow;
            s16x8 vv = *(const s16x8*)&SH[row * 256 + ((g ^ ((row >> 2) & 3)) << 4) + hh * 8];
            *(s16x8*)&Cb[cb + (long long)(tm * 256 + row) * ldc + tn * 256 + cch * 8] = vv;
        }
    } else {
        float* Cf = (float*)Cp;
        float* SHf = (float*)SH;  // [128 rows][32 groups of 8 floats] per half-pass
#pragma unroll
        for (int half = 0; half < 2; half++) {
            if (wm == half) {
#pragma unroll
                for (int tn_ = 0; tn_ < 2; tn_++) {
                    const int col = wn * 64 + tn_ * 32 + lcol;
                    const float bv = (HAS_BIAS && kIdx == 0) ? bias[tn * 256 + col] : 0.0f;
                    const int gg = col >> 3, cl = col & 7;
#pragma unroll
                    for (int tm_ = 0; tm_ < 4; tm_++) {
                        const int rbase = tm_ * 32 + 4 * lhi;  // row within half
#pragma unroll
                        for (int r = 0; r < 16; r++) {
                            const int row = rbase + (r & 3) + 8 * (r >> 2);
                            float v = acc[tm_][tn_][r] * scale + bv;
                            if (RELU) v = v > 0.f ? v : 0.f;
                            SHf[row * 256 + ((gg ^ ((row >> 2) & 3)) << 3) + cl] = v;
                        }
                    }
                }
            }
            BAR;
            // readout: 16 passes x (8 rows x 64 chunks of 16B); 1024B contiguous/row
            const int rr = tid >> 6, cc = tid & 63;
            const int g2 = cc >> 1, h2 = cc & 1;
#pragma unroll
            for (int pass = 0; pass < 16; pass++) {
                const int row = pass * 8 + rr;
                f32x4 vv = *(const f32x4*)&SHf[row * 256 + ((g2 ^ ((row >> 2) & 3)) << 3) + h2 * 4];
                *(f32x4*)&Cf[cb + (long long)(tm * 256 + half * 128 + row) * ldc + tn * 256 + cc * 4] = vv;
            }
            BAR;
        }
    }
#undef BAR
#undef PRIO1
#undef PRIO0
#undef WVM4
#undef WVM0
#undef WLG0
}

// ---------------- row softmax: bf16 [rows][2048] -> bf16, vectorized 8/thread -------

__global__ __launch_bounds__(256) void softmax_rows(const ushort* __restrict__ S,
                                                    ushort* __restrict__ P) {
    const int C = 2048;
    const long long row = blockIdx.x;
    const int tid = threadIdx.x;
    const ushort4* s4 = (const ushort4*)(S + row * C) + tid * 2;  // 8 contiguous elems
    ushort4 a = s4[0], bq = s4[1];
    float v[8];
    v[0] = b2f(a.x); v[1] = b2f(a.y); v[2] = b2f(a.z); v[3] = b2f(a.w);
    v[4] = b2f(bq.x); v[5] = b2f(bq.y); v[6] = b2f(bq.z); v[7] = b2f(bq.w);
    float mx = -1e30f;
#pragma unroll
    for (int i = 0; i < 8; i++) mx = fmaxf(mx, v[i]);
    __shared__ float red[256];
    red[tid] = mx;
    __syncthreads();
    for (int off = 128; off > 0; off >>= 1) {
        if (tid < off) red[tid] = fmaxf(red[tid], red[tid + off]);
        __syncthreads();
    }
    mx = red[0];
    __syncthreads();
    float sum = 0.f;
#pragma unroll
    for (int i = 0; i < 8; i++) {
        v[i] = __expf(v[i] - mx);
        sum += v[i];
    }
    red[tid] = sum;
    __syncthreads();
    for (int off = 128; off > 0; off >>= 1) {
        if (tid < off) red[tid] += red[tid + off];
        __syncthreads();
    }
    float inv = 1.f / red[0];
    ushort4 o0, o1;
    o0.x = f2b(v[0] * inv); o0.y = f2b(v[1] * inv); o0.z = f2b(v[2] * inv); o0.w = f2b(v[3] * inv);
    o1.x = f2b(v[4] * inv); o1.y = f2b(v[5] * inv); o1.z = f2b(v[6] * inv); o1.w = f2b(v[7] * inv);
    ushort4* p4 = (ushort4*)(P + row * C) + tid * 2;
    p4[0] = o0;
    p4[1] = o1;
}

// ---------------- fused residual(+partial-sum) + LayerNorm (D=1024) ----------------
// out = LN(X + Y + (Y2?)) ; Y2 nullable (split-K partial reduction fused here).
// R8: float4-vectorized loads/stores (G13).

__global__ __launch_bounds__(256) void residual_ln(const float* __restrict__ X,
                                                   const float* __restrict__ Y,
                                                   const float* __restrict__ Y2,
                                                   const float* __restrict__ g,
                                                   const float* __restrict__ be,
                                                   float* __restrict__ outf,
                                                   ushort* __restrict__ outb) {
    const int D = 1024;
    const long long row = blockIdx.x;
    const int tid = threadIdx.x;
    float4 xv = ((const float4*)(X + row * D))[tid];
    float4 yv = ((const float4*)(Y + row * D))[tid];
    xv.x += yv.x; xv.y += yv.y; xv.z += yv.z; xv.w += yv.w;
    if (Y2) {
        float4 y2v = ((const float4*)(Y2 + row * D))[tid];
        xv.x += y2v.x; xv.y += y2v.y; xv.z += y2v.z; xv.w += y2v.w;
    }
    float s = xv.x + xv.y + xv.z + xv.w;
    float s2 = xv.x * xv.x + xv.y * xv.y + xv.z * xv.z + xv.w * xv.w;
    __shared__ float r1[256], r2[256];
    r1[tid] = s;
    r2[tid] = s2;
    __syncthreads();
    for (int off = 128; off > 0; off >>= 1) {
        if (tid < off) {
            r1[tid] += r1[tid + off];
            r2[tid] += r2[tid + off];
        }
        __syncthreads();
    }
    float mu = r1[0] * (1.f / 1024.f);
    float var = r2[0] * (1.f / 1024.f) - mu * mu;
    float inv = rsqrtf(var + 1e-5f);
    float4 gv = ((const float4*)g)[tid];
    float4 bv = ((const float4*)be)[tid];
    float4 o;
    o.x = (xv.x - mu) * inv * gv.x + bv.x;
    o.y = (xv.y - mu) * inv * gv.y + bv.y;
    o.z = (xv.z - mu) * inv * gv.z + bv.z;
    o.w = (xv.w - mu) * inv * gv.w + bv.w;
    ((float4*)(outf + row * D))[tid] = o;
    if (outb) {
        ushort4 u;
        u.x = f2b(o.x); u.y = f2b(o.y); u.z = f2b(o.z); u.w = f2b(o.w);
        ((ushort4*)(outb + row * D))[tid] = u;
    }
}

// ---------------- launch ----------------

extern "C" void kernel_launch(void* const* d_in, const int* in_sizes, int n_in,
                              void* d_out, int out_size, void* d_ws, size_t ws_size,
                              hipStream_t stream) {
    const float* x  = (const float*)d_in[0];
    const float* wq = (const float*)d_in[1];
    const float* bq = (const float*)d_in[2];
    const float* wk = (const float*)d_in[3];
    const float* bk = (const float*)d_in[4];
    const float* wv = (const float*)d_in[5];
    const float* bv = (const float*)d_in[6];
    const float* wo = (const float*)d_in[7];
    const float* bo = (const float*)d_in[8];
    const float* w1 = (const float*)d_in[9];
    const float* b1 = (const float*)d_in[10];
    const float* w2 = (const float*)d_in[11];
    const float* b2 = (const float*)d_in[12];
    const float* g1 = (const float*)d_in[13];
    const float* be1 = (const float*)d_in[14];
    const float* g2 = (const float*)d_in[15];
    const float* be2 = (const float*)d_in[16];
    float* out = (float*)d_out;
    char* ws = (char*)d_ws;

    const int Bz = 4, S = 2048, D = 1024, F = 4096;
    const int T = Bz * S;  // 8192 rows
    const size_t MBy = 1024ull * 1024ull;

    // workspace layout (byte offsets), lifetime-based reuse; peak 201 MB
    ushort* qkvT = (ushort*)(ws + 0);        // 6 MB  [3072][1024]; woT follows contiguously
    ushort* woT  = (ushort*)(ws + 6 * MBy);  // 2 MB
    ushort* w1T  = (ushort*)(ws + 8 * MBy);  // 8 MB   [F][D]
    ushort* w2T  = (ushort*)(ws + 16 * MBy); // 8 MB   [D][F]
    float*  bqkv = (float*)(ws + 24 * MBy);  // 12 KB  (dead after QKV gemm)
    ushort* xb   = (ushort*)(ws + 25 * MBy); // 16 MB  (dead after QKV gemm)
    ushort* qkv  = (ushort*)(ws + 41 * MBy); // 48 MB  [T][3072] (dead after scores+vT)
    ushort* vT   = (ushort*)(ws + 89 * MBy); // 16 MB  [B][D][S] (dead after ctx)
    ushort* scb  = (ushort*)(ws + 105 * MBy); // 32 MB bf16 scores (dead after softmax)
    ushort* attn = (ushort*)(ws + 169 * MBy); // 32 MB (dead after ctx)
    // reuse (non-overlapping lifetimes):
    float*  ctx0 = (float*)(ws + 105 * MBy); // 32 MB over scb (dead after add2_cast)
    float*  ctx1 = (float*)(ws + 137 * MBy); // 32 MB (dead after add2_cast)
    ushort* ctxb = (ushort*)(ws + 25 * MBy); // 16 MB over xb (dead after wo)
    float*  ao0 = (float*)(ws + 105 * MBy);  // 32 MB over ctx0 (dead after ln1)
    float*  ao1 = (float*)(ws + 137 * MBy);  // 32 MB (dead after ln1)
    float*  x1  = (float*)(ws + 41 * MBy);   // 32 MB over qkv (live to ln2)
    ushort* x1b = (ushort*)(ws + 73 * MBy);  // 16 MB over qkv (dead after ffn1)
    ushort* h   = (ushort*)(ws + 105 * MBy); // 64 MB over ao (after ln1)
    float*  ff0 = (float*)(ws + 169 * MBy);  // 32 MB over attn
    float*  ff1 = (float*)(ws + 73 * MBy);   // 32 MB over x1b+vT (both dead by ffn2)

    dim3 b32(32, 8);

    // 1) cast x -> bf16
    cast_f2b4<<<(T * D) / 1024, 256, 0, stream>>>(x, xb, (long long)(T * D) / 4);

    // 2) transpose-cast weights: wq/wk/wv/wo -> [qkvT|woT] in ONE dispatch; w1, w2
    transpose4_to_bf16<<<dim3(32, 32, 4), b32, 0, stream>>>(wq, wk, wv, wo, qkvT);
    transpose_to_bf16<float><<<dim3(128, 32, 1), b32, 0, stream>>>(w1, w1T, D, F, F, 0, 0);
    transpose_to_bf16<float><<<dim3(32, 128, 1), b32, 0, stream>>>(w2, w2T, F, D, D, 0, 0);

    // 3) fused bias vector [bq|bk|bv]
    concat3<<<12, 256, 0, stream>>>(bq, bk, bv, bqkv);

    // 4) fused QKV projection: [T][1024] x [3072][1024]^T -> [T][3072] bf16 (384 blocks)
    gemm256<1, 0, 1><<<dim3(3 * D / 256, T / 256, 1), 512, 0, stream>>>(
        xb, qkvT, qkv, bqkv, D, 1, 1.f, D, D, 3 * D, 0, 0, 0, 0);

    // 5) V^T per batch: qkv v-slice [S][1024] (ld 3072) -> [D][S]
    transpose_to_bf16<ushort><<<dim3(D / 32, S / 32, Bz), b32, 0, stream>>>(
        qkv + 2048, vT, S, D, 3 * D, (long long)S * 3 * D, (long long)S * D);

    // 6) scores = Q K^T / 32 -> bf16; A=q, B=k slices of qkv (ld 3072) (256 blocks)
    gemm256<1, 0, 0><<<dim3(S / 256, S / 256, Bz), 512, 0, stream>>>(
        qkv, qkv + 1024, scb, nullptr, D, 1, 0.03125f, 3 * D, 3 * D, S,
        (long long)S * 3 * D, (long long)S * 3 * D, (long long)S * S, 0);

    // 7) softmax rows -> bf16 attn
    softmax_rows<<<T, 256, 0, stream>>>(scb, attn);

    // 8) ctx partials = attn @ V (BT = V^T [D][S]), split-K=2 -> fp32 (256 blocks)
    gemm256<0, 0, 0><<<dim3(D / 256, S / 256, Bz * 2), 512, 0, stream>>>(
        attn, vT, ctx0, nullptr, S, 2, 1.f, S, S, D,
        (long long)S * S, (long long)D * S, (long long)S * D, (long long)(ctx1 - ctx0));

    // 8b) ctx = ctx0 + ctx1 -> bf16
    add2_cast<<<(T * D) / 1024, 256, 0, stream>>>(ctx0, ctx1, ctxb, (long long)(T * D) / 4);

    // 9) attn_out partials = ctx @ wo^T (+bo chunk 0), split-K=2 (256 blocks)
    gemm256<0, 0, 1><<<dim3(D / 256, T / 256, 2), 512, 0, stream>>>(
        ctxb, woT, ao0, bo, D, 2, 1.f, D, D, D, 0, 0, 0, (long long)(ao1 - ao0));

    // 10) x1 = LN(x + ao0 + ao1) -> fp32 + bf16 (split-K reduction fused)
    residual_ln<<<T, 256, 0, stream>>>(x, ao0, ao1, g1, be1, x1, x1b);

    // 11) h = relu(x1 @ w1 + b1) (bf16, 512 blocks)
    gemm256<1, 1, 1><<<dim3(F / 256, T / 256, 1), 512, 0, stream>>>(
        x1b, w1T, h, b1, D, 1, 1.f, D, D, F, 0, 0, 0, 0);

    // 12) ff partials = h @ w2 (+b2 on chunk 0), split-K=2 (256 blocks)
    gemm256<0, 0, 1><<<dim3(D / 256, T / 256, 2), 512, 0, stream>>>(
        h, w2T, ff0, b2, F, 2, 1.f, F, F, D, 0, 0, 0, (long long)(ff1 - ff0));

    // 13) out = LN(x1 + ff0 + ff1) -> d_out fp32 (split-K reduction fused)
    residual_ln<<<T, 256, 0, stream>>>(x1, ff0, ff1, g2, be2, out, nullptr);
}